// Round 5
// baseline (502.542 us; speedup 1.0000x reference)
//
#include <hip/hip_runtime.h>
#include <hip/hip_cooperative_groups.h>

namespace cg = cooperative_groups;

#define TPB 512
#define GRID 256   // 64 b * (2048/512) chunks; exactly 1 block/CU -> coop launch always fits

// Reduce 4 per-lane values (indexed by u=0..3) across the 64-lane wave.
// Result: lane holds the wave-total of value index (lane & 3).
__device__ __forceinline__ float redu4(float a0, float a1, float a2, float a3, int lane) {
  const bool b1 = lane & 1;
  float t01 = b1 ? a0 : a1;
  float r01 = __shfl_xor(t01, 1, 64);
  float s01 = (b1 ? a1 : a0) + r01;           // value (lane&1), summed over lane pair
  float t23 = b1 ? a2 : a3;
  float r23 = __shfl_xor(t23, 1, 64);
  float s23 = (b1 ? a3 : a2) + r23;           // value 2+(lane&1)
  const bool b2 = lane & 2;
  float t = b2 ? s01 : s23;
  float r = __shfl_xor(t, 2, 64);
  float s = (b2 ? s23 : s01) + r;             // value (lane&3), summed over quad
  s += __shfl_xor(s, 4, 64);
  s += __shfl_xor(s, 8, 64);
  s += __shfl_xor(s, 16, 64);
  s += __shfl_xor(s, 32, 64);
  return s;
}

// amdgpu_waves_per_eu(2,2): pin occupancy target to exactly 2 waves/EU
// (= one 512-thread coop block per CU). Default RA targeted 4 waves/EU,
// capped VGPR at 128, and spilled ~1.17 GB/dispatch of scratch traffic
// (dur 483us == 1.18GB / 2.45TB/s -> purely spill-bound). Budget 256 VGPR
// fits the ~170 live floats with zero spill.
__global__ void __launch_bounds__(TPB) __attribute__((amdgpu_waves_per_eu(2, 2)))
risnet_kernel(
    const float* __restrict__ channel,
    const float* __restrict__ We1, const float* __restrict__ be1,
    const float* __restrict__ We,  const float* __restrict__ be,
    const float* __restrict__ Wo1, const float* __restrict__ bo1,
    const float* __restrict__ Wo,  const float* __restrict__ bo,
    const float* __restrict__ W8,  const float* __restrict__ b8,
    float* __restrict__ out, float* __restrict__ part)
{
  const int tid  = threadIdx.x;
  const int lane = tid & 63;
  const int wv   = tid >> 6;                  // 0..7
  const int b    = blockIdx.x >> 2;           // 0..63
  const int blk  = blockIdx.x & 3;            // 0..3
  const int n    = (blk << 9) | tid;          // 0..2047

  __shared__ __align__(16) float wE[6*576];     // layers 1..6 ego weights [16][36]
  __shared__ __align__(16) float wO[6*576];
  __shared__ __align__(16) float biasE[16][4];  // [h][u] folded bias (be + eg/og terms)
  __shared__ __align__(16) float biasO[16][4];
  __shared__ float red[8][64];                  // per-wave partials: conv*32 + j*4 + u
  __shared__ float gv[64];                      // per-b means: ego-g (0..31), opp-g (32..63)
  __shared__ float fin;

  // stage all conv weights (layers 1..6) into LDS once
  for (int i = tid; i < 6*576; i += TPB) { wE[i] = We[i]; wO[i] = Wo[i]; }

  // per-thread channel slice: ch_[u][f]
  float ch_[4][4];
#pragma unroll
  for (int u = 0; u < 4; ++u)
#pragma unroll
    for (int f = 0; f < 4; ++f)
      ch_[u][f] = channel[((b*4 + u)*4 + f)*2048 + n];

  cg::grid_group grid = cg::this_grid();

  float el_[4][8], ol_[4][8];

  // ---------------- layer 0 (Cin = 4, feats = ch) ----------------
  {
    float opl[4][8];
#pragma unroll
    for (int h = 0; h < 16; ++h) {
      const float4 w = *(const float4*)(We1 + h*4);
      const float bs = be1[h];
      float a[4];
#pragma unroll
      for (int u = 0; u < 4; ++u)
        a[u] = fmaxf(bs + w.x*ch_[u][0] + w.y*ch_[u][1] + w.z*ch_[u][2] + w.w*ch_[u][3], 0.f);
      if (h < 8) {
#pragma unroll
        for (int u = 0; u < 4; ++u) el_[u][h] = a[u];
      } else {
        float s = redu4(a[0], a[1], a[2], a[3], lane);
        if (lane < 4) red[wv][(h-8)*4 + lane] = s;
      }
    }
#pragma unroll
    for (int h = 0; h < 16; ++h) {
      const float4 w = *(const float4*)(Wo1 + h*4);
      const float bs = bo1[h];
      float a[4];
#pragma unroll
      for (int u = 0; u < 4; ++u)
        a[u] = fmaxf(bs + w.x*ch_[u][0] + w.y*ch_[u][1] + w.z*ch_[u][2] + w.w*ch_[u][3], 0.f);
      if (h < 8) {
#pragma unroll
        for (int u = 0; u < 4; ++u) opl[u][h] = a[u];
      } else {
        float s = redu4(a[0], a[1], a[2], a[3], lane);
        if (lane < 4) red[wv][32 + (h-8)*4 + lane] = s;
      }
    }
#pragma unroll
    for (int j = 0; j < 8; ++j) {
      float s = opl[0][j] + opl[1][j] + opl[2][j] + opl[3][j];
#pragma unroll
      for (int u = 0; u < 4; ++u) ol_[u][j] = (s - opl[u][j]) * (1.f/3.f);
    }
  }
  __syncthreads();
  if (tid < 64) {
    float s = 0.f;
#pragma unroll
    for (int w = 0; w < 8; ++w) s += red[w][tid];
    __hip_atomic_store(&part[((0*64 + b)*4 + blk)*64 + tid], s,
                       __ATOMIC_RELAXED, __HIP_MEMORY_SCOPE_AGENT);
  }
  grid.sync();

  // ---------------- layers 1..6 (Cin = 36) ----------------
  for (int L = 1; L < 7; ++L) {
    const float* __restrict__ wEl = &wE[(L-1)*576];
    const float* __restrict__ wOl = &wO[(L-1)*576];
    const int par_r = (L-1) & 1;   // parity written by layer L-1
    const int par_w = L & 1;

    // gather this-b global sums (4 block partials, fixed order) -> means
    if (tid < 64) {
      float s = 0.f;
#pragma unroll
      for (int k = 0; k < 4; ++k)
        s += __hip_atomic_load(&part[((par_r*64 + b)*4 + k)*64 + tid],
                               __ATOMIC_RELAXED, __HIP_MEMORY_SCOPE_AGENT);
      gv[tid] = s * (1.f/2048.f);
    }
    __syncthreads();

    // fold eg/og into per-(conv,u,h) bias
    if (tid < 128) {
      const int cv = tid >> 6;
      const int rr = tid & 63;
      const int u  = rr & 3;
      const int h  = rr >> 2;
      const float* W = cv ? wOl : wEl;
      float bias = cv ? bo[(L-1)*16 + h] : be[(L-1)*16 + h];
#pragma unroll
      for (int j = 0; j < 8; ++j) {
        const float eg = gv[j*4 + u];
        const float so = gv[32+j*4+0] + gv[32+j*4+1] + gv[32+j*4+2] + gv[32+j*4+3];
        const float og = (so - gv[32 + j*4 + u]) * (1.f/3.f);
        bias += W[h*36 + 12 + j] * eg + W[h*36 + 28 + j] * og;
      }
      if (cv) biasO[h][u] = bias; else biasE[h][u] = bias;
    }
    __syncthreads();

    float en[4][8], opl[4][8];
    // ego conv: live columns ch 0..3, el 4..11, ol 20..27; eg/og folded into bias
#pragma unroll
    for (int h = 0; h < 16; ++h) {
      const float4* wr = (const float4*)(wEl + h*36);
      const float4 w0 = wr[0], w1 = wr[1], w2 = wr[2], w5 = wr[5], w6 = wr[6];
      const float4 bb = *(const float4*)(&biasE[h][0]);
      float a[4] = {bb.x, bb.y, bb.z, bb.w};
#pragma unroll
      for (int u = 0; u < 4; ++u) {
        float v = a[u];
        v += w0.x*ch_[u][0] + w0.y*ch_[u][1] + w0.z*ch_[u][2] + w0.w*ch_[u][3];
        v += w1.x*el_[u][0] + w1.y*el_[u][1] + w1.z*el_[u][2] + w1.w*el_[u][3];
        v += w2.x*el_[u][4] + w2.y*el_[u][5] + w2.z*el_[u][6] + w2.w*el_[u][7];
        v += w5.x*ol_[u][0] + w5.y*ol_[u][1] + w5.z*ol_[u][2] + w5.w*ol_[u][3];
        v += w6.x*ol_[u][4] + w6.y*ol_[u][5] + w6.z*ol_[u][6] + w6.w*ol_[u][7];
        a[u] = fmaxf(v, 0.f);
      }
      if (h < 8) {
#pragma unroll
        for (int u = 0; u < 4; ++u) en[u][h] = a[u];
      } else {
        float s = redu4(a[0], a[1], a[2], a[3], lane);
        if (lane < 4) red[wv][(h-8)*4 + lane] = s;
      }
    }
    // opp conv
#pragma unroll
    for (int h = 0; h < 16; ++h) {
      const float4* wr = (const float4*)(wOl + h*36);
      const float4 w0 = wr[0], w1 = wr[1], w2 = wr[2], w5 = wr[5], w6 = wr[6];
      const float4 bb = *(const float4*)(&biasO[h][0]);
      float a[4] = {bb.x, bb.y, bb.z, bb.w};
#pragma unroll
      for (int u = 0; u < 4; ++u) {
        float v = a[u];
        v += w0.x*ch_[u][0] + w0.y*ch_[u][1] + w0.z*ch_[u][2] + w0.w*ch_[u][3];
        v += w1.x*el_[u][0] + w1.y*el_[u][1] + w1.z*el_[u][2] + w1.w*el_[u][3];
        v += w2.x*el_[u][4] + w2.y*el_[u][5] + w2.z*el_[u][6] + w2.w*el_[u][7];
        v += w5.x*ol_[u][0] + w5.y*ol_[u][1] + w5.z*ol_[u][2] + w5.w*ol_[u][3];
        v += w6.x*ol_[u][4] + w6.y*ol_[u][5] + w6.z*ol_[u][6] + w6.w*ol_[u][7];
        a[u] = fmaxf(v, 0.f);
      }
      if (h < 8) {
#pragma unroll
        for (int u = 0; u < 4; ++u) opl[u][h] = a[u];
      } else {
        float s = redu4(a[0], a[1], a[2], a[3], lane);
        if (lane < 4) red[wv][32 + (h-8)*4 + lane] = s;
      }
    }
    // LOO + commit new local feats
#pragma unroll
    for (int j = 0; j < 8; ++j) {
      float s = opl[0][j] + opl[1][j] + opl[2][j] + opl[3][j];
#pragma unroll
      for (int u = 0; u < 4; ++u) ol_[u][j] = (s - opl[u][j]) * (1.f/3.f);
    }
#pragma unroll
    for (int u = 0; u < 4; ++u)
#pragma unroll
      for (int j = 0; j < 8; ++j) el_[u][j] = en[u][j];

    __syncthreads();
    if (tid < 64) {
      float s = 0.f;
#pragma unroll
      for (int w = 0; w < 8; ++w) s += red[w][tid];
      __hip_atomic_store(&part[((par_w*64 + b)*4 + blk)*64 + tid], s,
                         __ATOMIC_RELAXED, __HIP_MEMORY_SCOPE_AGENT);
    }
    grid.sync();
  }

  // ---------------- final 1x1 conv + mean over users ----------------
  // layer 6 wrote parity 0
  if (tid < 64) {
    float s = 0.f;
#pragma unroll
    for (int k = 0; k < 4; ++k)
      s += __hip_atomic_load(&part[((0*64 + b)*4 + k)*64 + tid],
                             __ATOMIC_RELAXED, __HIP_MEMORY_SCOPE_AGENT);
    gv[tid] = s * (1.f/2048.f);
  }
  __syncthreads();
  if (tid == 0) {
    float s = b8[0];
#pragma unroll
    for (int j = 0; j < 8; ++j) {
      const float so = gv[32+j*4+0] + gv[32+j*4+1] + gv[32+j*4+2] + gv[32+j*4+3];
#pragma unroll
      for (int u = 0; u < 4; ++u) {
        const float eg = gv[j*4 + u];
        const float og = (so - gv[32 + j*4 + u]) * (1.f/3.f);
        s += 0.25f * (W8[12 + j] * eg + W8[28 + j] * og);
      }
    }
    fin = s;
  }
  __syncthreads();
  float r = fin;
#pragma unroll
  for (int u = 0; u < 4; ++u) {
    float t = 0.f;
#pragma unroll
    for (int c = 0; c < 4; ++c) t += W8[c] * ch_[u][c];
#pragma unroll
    for (int j = 0; j < 8; ++j) t += W8[4 + j] * el_[u][j] + W8[20 + j] * ol_[u][j];
    r += 0.25f * t;
  }
  out[b*2048 + n] = r * 3.14159265358979f;
}

extern "C" void kernel_launch(void* const* d_in, const int* in_sizes, int n_in,
                              void* d_out, int out_size, void* d_ws, size_t ws_size,
                              hipStream_t stream) {
  const float* channel = (const float*)d_in[0];
  const float* We1 = (const float*)d_in[1];
  const float* be1 = (const float*)d_in[2];
  const float* We  = (const float*)d_in[3];
  const float* be  = (const float*)d_in[4];
  const float* Wo1 = (const float*)d_in[5];
  const float* bo1 = (const float*)d_in[6];
  const float* Wo  = (const float*)d_in[7];
  const float* bo  = (const float*)d_in[8];
  const float* W8  = (const float*)d_in[9];
  const float* b8  = (const float*)d_in[10];
  float* out  = (float*)d_out;
  float* part = (float*)d_ws;   // 2 parity * 64 b * 4 blk * 64 vals * 4B = 131072 B

  void* args[] = { (void*)&channel, (void*)&We1, (void*)&be1, (void*)&We, (void*)&be,
                   (void*)&Wo1, (void*)&bo1, (void*)&Wo, (void*)&bo,
                   (void*)&W8, (void*)&b8, (void*)&out, (void*)&part };
  hipLaunchCooperativeKernel((void*)risnet_kernel, dim3(GRID), dim3(TPB), args, 0, stream);
}

// Round 6
// 283.831 us; speedup vs baseline: 1.7706x; 1.7706x over previous
//
#include <hip/hip_runtime.h>
#include <hip/hip_cooperative_groups.h>

namespace cg = cooperative_groups;

#define TPB 512
#define GRID 256   // 64 b * 4 n-chunks; 1 block/CU -> coop launch always fits

// Reduce 4 per-lane values (indexed by u=0..3) across the 64-lane wave.
// Result: lane holds the wave-total of value index (lane & 3).
__device__ __forceinline__ float redu4(float a0, float a1, float a2, float a3, int lane) {
  const bool b1 = lane & 1;
  float t01 = b1 ? a0 : a1;
  float r01 = __shfl_xor(t01, 1, 64);
  float s01 = (b1 ? a1 : a0) + r01;
  float t23 = b1 ? a2 : a3;
  float r23 = __shfl_xor(t23, 1, 64);
  float s23 = (b1 ? a3 : a2) + r23;
  const bool b2 = lane & 2;
  float t = b2 ? s01 : s23;
  float r = __shfl_xor(t, 2, 64);
  float s = (b2 ? s23 : s01) + r;
  s += __shfl_xor(s, 4, 64);
  s += __shfl_xor(s, 8, 64);
  s += __shfl_xor(s, 16, 64);
  s += __shfl_xor(s, 32, 64);
  return s;
}

// Spill fix (r5 post-mortem): RA is pinned at 128 VGPR (two occupancy
// attributes ignored) and spilled ~1.17 GB/dispatch. Instead of raising the
// budget, reduce peak pressure: both conv outputs stream through LDS
// (fb[conv][tid][33], pad -> bank (tid+idx)%32, conflict-free, same-thread
// RAW so no barrier), weights read via wave-uniform s_loads (no LDS stage).
// Live regs during convs: ch16+el32+ol32+temps ~= 100 < 128 -> no spill.
__global__ void __launch_bounds__(TPB) risnet_kernel(
    const float* __restrict__ channel,
    const float* __restrict__ We1, const float* __restrict__ be1,
    const float* __restrict__ We,  const float* __restrict__ be,
    const float* __restrict__ Wo1, const float* __restrict__ bo1,
    const float* __restrict__ Wo,  const float* __restrict__ bo,
    const float* __restrict__ W8,  const float* __restrict__ b8,
    float* __restrict__ out, float* __restrict__ part)
{
  const int tid  = threadIdx.x;
  const int lane = tid & 63;
  const int wv   = tid >> 6;                  // 0..7
  const int b    = blockIdx.x >> 2;           // 0..63
  const int blk  = blockIdx.x & 3;            // 0..3
  const int n    = (blk << 9) | tid;          // 0..2047

  __shared__ __align__(16) float fb[2][TPB][33];  // conv outputs: [0]=ego(en), [1]=opp(opl)
  __shared__ __align__(16) float biasE[16][4];    // [h][u] folded bias
  __shared__ __align__(16) float biasO[16][4];
  __shared__ float red[8][64];                    // per-wave partials: conv*32 + j*4 + u
  __shared__ float gv[64];                        // per-b means: ego-g 0..31, opp-g 32..63
  __shared__ float fin;

  // per-thread channel slice: ch_[u][f]
  float ch_[4][4];
#pragma unroll
  for (int u = 0; u < 4; ++u)
#pragma unroll
    for (int f = 0; f < 4; ++f)
      ch_[u][f] = channel[((b*4 + u)*4 + f)*2048 + n];

  cg::grid_group grid = cg::this_grid();

  float el_[4][8], ol_[4][8];

  // ---------------- layer 0 (Cin = 4, feats = ch; all in regs) ----------------
  {
    float opl[4][8];
#pragma unroll
    for (int h = 0; h < 16; ++h) {
      const float4 w = *(const float4*)(We1 + h*4);
      const float bs = be1[h];
      float a[4];
#pragma unroll
      for (int u = 0; u < 4; ++u)
        a[u] = fmaxf(bs + w.x*ch_[u][0] + w.y*ch_[u][1] + w.z*ch_[u][2] + w.w*ch_[u][3], 0.f);
      if (h < 8) {
#pragma unroll
        for (int u = 0; u < 4; ++u) el_[u][h] = a[u];
      } else {
        float s = redu4(a[0], a[1], a[2], a[3], lane);
        if (lane < 4) red[wv][(h-8)*4 + lane] = s;
      }
    }
#pragma unroll
    for (int h = 0; h < 16; ++h) {
      const float4 w = *(const float4*)(Wo1 + h*4);
      const float bs = bo1[h];
      float a[4];
#pragma unroll
      for (int u = 0; u < 4; ++u)
        a[u] = fmaxf(bs + w.x*ch_[u][0] + w.y*ch_[u][1] + w.z*ch_[u][2] + w.w*ch_[u][3], 0.f);
      if (h < 8) {
#pragma unroll
        for (int u = 0; u < 4; ++u) opl[u][h] = a[u];
      } else {
        float s = redu4(a[0], a[1], a[2], a[3], lane);
        if (lane < 4) red[wv][32 + (h-8)*4 + lane] = s;
      }
    }
#pragma unroll
    for (int j = 0; j < 8; ++j) {
      float s = opl[0][j] + opl[1][j] + opl[2][j] + opl[3][j];
#pragma unroll
      for (int u = 0; u < 4; ++u) ol_[u][j] = (s - opl[u][j]) * (1.f/3.f);
    }
  }
  __syncthreads();
  if (tid < 64) {
    float s = 0.f;
#pragma unroll
    for (int w = 0; w < 8; ++w) s += red[w][tid];
    __hip_atomic_store(&part[((0*64 + b)*4 + blk)*64 + tid], s,
                       __ATOMIC_RELAXED, __HIP_MEMORY_SCOPE_AGENT);
  }
  grid.sync();

  // ---------------- layers 1..6 (Cin = 36) ----------------
  for (int L = 1; L < 7; ++L) {
    const float* __restrict__ wEl = We + (L-1)*576;   // [16][36], wave-uniform -> s_loads
    const float* __restrict__ wOl = Wo + (L-1)*576;
    const int par_r = (L-1) & 1;
    const int par_w = L & 1;

    // gather this-b global sums (4 block partials, fixed order) -> means
    if (tid < 64) {
      float s = 0.f;
#pragma unroll
      for (int k = 0; k < 4; ++k)
        s += __hip_atomic_load(&part[((par_r*64 + b)*4 + k)*64 + tid],
                               __ATOMIC_RELAXED, __HIP_MEMORY_SCOPE_AGENT);
      gv[tid] = s * (1.f/2048.f);
    }
    __syncthreads();

    // fold eg/og into per-(conv,u,h) bias
    if (tid < 128) {
      const int cv = tid >> 6;
      const int rr = tid & 63;
      const int u  = rr & 3;
      const int h  = rr >> 2;
      const float* W = cv ? wOl : wEl;
      float bias = cv ? bo[(L-1)*16 + h] : be[(L-1)*16 + h];
#pragma unroll
      for (int j = 0; j < 8; ++j) {
        const float eg = gv[j*4 + u];
        const float so = gv[32+j*4+0] + gv[32+j*4+1] + gv[32+j*4+2] + gv[32+j*4+3];
        const float og = (so - gv[32 + j*4 + u]) * (1.f/3.f);
        bias += W[h*36 + 12 + j] * eg + W[h*36 + 28 + j] * og;
      }
      if (cv) biasO[h][u] = bias; else biasE[h][u] = bias;
    }
    __syncthreads();

    // ego conv -> fb[0]; live cols: ch 0..3, el 4..11, ol 20..27
#pragma unroll
    for (int h = 0; h < 16; ++h) {
      const float4* wr = (const float4*)(wEl + h*36);
      const float4 w0 = wr[0], w1 = wr[1], w2 = wr[2], w5 = wr[5], w6 = wr[6];
      const float4 bb = *(const float4*)(&biasE[h][0]);
      float a[4] = {bb.x, bb.y, bb.z, bb.w};
#pragma unroll
      for (int u = 0; u < 4; ++u) {
        float v = a[u];
        v += w0.x*ch_[u][0] + w0.y*ch_[u][1] + w0.z*ch_[u][2] + w0.w*ch_[u][3];
        v += w1.x*el_[u][0] + w1.y*el_[u][1] + w1.z*el_[u][2] + w1.w*el_[u][3];
        v += w2.x*el_[u][4] + w2.y*el_[u][5] + w2.z*el_[u][6] + w2.w*el_[u][7];
        v += w5.x*ol_[u][0] + w5.y*ol_[u][1] + w5.z*ol_[u][2] + w5.w*ol_[u][3];
        v += w6.x*ol_[u][4] + w6.y*ol_[u][5] + w6.z*ol_[u][6] + w6.w*ol_[u][7];
        a[u] = fmaxf(v, 0.f);
      }
      if (h < 8) {
#pragma unroll
        for (int u = 0; u < 4; ++u) fb[0][tid][h*4 + u] = a[u];
      } else {
        float s = redu4(a[0], a[1], a[2], a[3], lane);
        if (lane < 4) red[wv][(h-8)*4 + lane] = s;
      }
    }
    // opp conv -> fb[1]
#pragma unroll
    for (int h = 0; h < 16; ++h) {
      const float4* wr = (const float4*)(wOl + h*36);
      const float4 w0 = wr[0], w1 = wr[1], w2 = wr[2], w5 = wr[5], w6 = wr[6];
      const float4 bb = *(const float4*)(&biasO[h][0]);
      float a[4] = {bb.x, bb.y, bb.z, bb.w};
#pragma unroll
      for (int u = 0; u < 4; ++u) {
        float v = a[u];
        v += w0.x*ch_[u][0] + w0.y*ch_[u][1] + w0.z*ch_[u][2] + w0.w*ch_[u][3];
        v += w1.x*el_[u][0] + w1.y*el_[u][1] + w1.z*el_[u][2] + w1.w*el_[u][3];
        v += w2.x*el_[u][4] + w2.y*el_[u][5] + w2.z*el_[u][6] + w2.w*el_[u][7];
        v += w5.x*ol_[u][0] + w5.y*ol_[u][1] + w5.z*ol_[u][2] + w5.w*ol_[u][3];
        v += w6.x*ol_[u][4] + w6.y*ol_[u][5] + w6.z*ol_[u][6] + w6.w*ol_[u][7];
        a[u] = fmaxf(v, 0.f);
      }
      if (h < 8) {
#pragma unroll
        for (int u = 0; u < 4; ++u) fb[1][tid][h*4 + u] = a[u];
      } else {
        float s = redu4(a[0], a[1], a[2], a[3], lane);
        if (lane < 4) red[wv][32 + (h-8)*4 + lane] = s;
      }
    }
    // read back own rows (same-thread RAW through LDS; no barrier needed):
    // el <- fb[0], LOO(opl=fb[1]) -> ol
#pragma unroll
    for (int j = 0; j < 8; ++j) {
      const float o0 = fb[1][tid][j*4+0], o1 = fb[1][tid][j*4+1];
      const float o2 = fb[1][tid][j*4+2], o3 = fb[1][tid][j*4+3];
      const float s = o0 + o1 + o2 + o3;
      ol_[0][j] = (s - o0) * (1.f/3.f);
      ol_[1][j] = (s - o1) * (1.f/3.f);
      ol_[2][j] = (s - o2) * (1.f/3.f);
      ol_[3][j] = (s - o3) * (1.f/3.f);
#pragma unroll
      for (int u = 0; u < 4; ++u) el_[u][j] = fb[0][tid][j*4 + u];
    }

    __syncthreads();
    if (tid < 64) {
      float s = 0.f;
#pragma unroll
      for (int w = 0; w < 8; ++w) s += red[w][tid];
      __hip_atomic_store(&part[((par_w*64 + b)*4 + blk)*64 + tid], s,
                         __ATOMIC_RELAXED, __HIP_MEMORY_SCOPE_AGENT);
    }
    grid.sync();
  }

  // ---------------- final 1x1 conv + mean over users ----------------
  // layer 6 wrote parity 0
  if (tid < 64) {
    float s = 0.f;
#pragma unroll
    for (int k = 0; k < 4; ++k)
      s += __hip_atomic_load(&part[((0*64 + b)*4 + k)*64 + tid],
                             __ATOMIC_RELAXED, __HIP_MEMORY_SCOPE_AGENT);
    gv[tid] = s * (1.f/2048.f);
  }
  __syncthreads();
  if (tid == 0) {
    float s = b8[0];
#pragma unroll
    for (int j = 0; j < 8; ++j) {
      const float so = gv[32+j*4+0] + gv[32+j*4+1] + gv[32+j*4+2] + gv[32+j*4+3];
#pragma unroll
      for (int u = 0; u < 4; ++u) {
        const float eg = gv[j*4 + u];
        const float og = (so - gv[32 + j*4 + u]) * (1.f/3.f);
        s += 0.25f * (W8[12 + j] * eg + W8[28 + j] * og);
      }
    }
    fin = s;
  }
  __syncthreads();
  float r = fin;
#pragma unroll
  for (int u = 0; u < 4; ++u) {
    float t = 0.f;
#pragma unroll
    for (int c = 0; c < 4; ++c) t += W8[c] * ch_[u][c];
#pragma unroll
    for (int j = 0; j < 8; ++j) t += W8[4 + j] * el_[u][j] + W8[20 + j] * ol_[u][j];
    r += 0.25f * t;
  }
  out[b*2048 + n] = r * 3.14159265358979f;
}

extern "C" void kernel_launch(void* const* d_in, const int* in_sizes, int n_in,
                              void* d_out, int out_size, void* d_ws, size_t ws_size,
                              hipStream_t stream) {
  const float* channel = (const float*)d_in[0];
  const float* We1 = (const float*)d_in[1];
  const float* be1 = (const float*)d_in[2];
  const float* We  = (const float*)d_in[3];
  const float* be  = (const float*)d_in[4];
  const float* Wo1 = (const float*)d_in[5];
  const float* bo1 = (const float*)d_in[6];
  const float* Wo  = (const float*)d_in[7];
  const float* bo  = (const float*)d_in[8];
  const float* W8  = (const float*)d_in[9];
  const float* b8  = (const float*)d_in[10];
  float* out  = (float*)d_out;
  float* part = (float*)d_ws;   // 2 parity * 64 b * 4 blk * 64 vals * 4B = 131072 B

  void* args[] = { (void*)&channel, (void*)&We1, (void*)&be1, (void*)&We, (void*)&be,
                   (void*)&Wo1, (void*)&bo1, (void*)&Wo, (void*)&bo,
                   (void*)&W8, (void*)&b8, (void*)&out, (void*)&part };
  hipLaunchCooperativeKernel((void*)risnet_kernel, dim3(GRID), dim3(TPB), args, 0, stream);
}